// Round 1
// baseline (1140.309 us; speedup 1.0000x reference)
//
#include <hip/hip_runtime.h>

#define N_NODES 50000
#define E_EDGES 600000
#define LLM_DIM 640
#define HIDDEN 128
#define POUT 112

// ---------------- degree kernels ----------------
__global__ void deg_init(float* __restrict__ dis) {
    int i = blockIdx.x * 256 + threadIdx.x;
    if (i < N_NODES) dis[i] = 1.0f;
}

__global__ void deg_count(const int* __restrict__ eidx, float* __restrict__ dis) {
    int e = blockIdx.x * 256 + threadIdx.x;
    if (e < E_EDGES) atomicAdd(&dis[eidx[E_EDGES + e]], 1.0f);
}

__global__ void deg_rsqrt(float* __restrict__ dis) {
    int i = blockIdx.x * 256 + threadIdx.x;
    if (i < N_NODES) dis[i] = rsqrtf(dis[i]);
}

// ---------------- projection GEMM: X[:, :112] = llm @ projW + b ----------------
// BM=128 rows/block, BN=112 (full), BK=32. 256 thr, each 8 rows x 7 cols.
__global__ __launch_bounds__(256) void proj_gemm(const float* __restrict__ A,
                                                 const float* __restrict__ W,
                                                 const float* __restrict__ bias,
                                                 float* __restrict__ X) {
    __shared__ float As[32][129];   // [k][row], pad breaks pow2 strides
    __shared__ float Bs[32][114];   // [k][col]
    const int tid = threadIdx.x;
    const int tr = tid >> 4;        // 0..15
    const int tc = tid & 15;        // 0..15
    const int row0 = blockIdx.x * 128;

    float acc[8][7];
#pragma unroll
    for (int i = 0; i < 8; i++)
#pragma unroll
        for (int j = 0; j < 7; j++) acc[i][j] = 0.f;

    for (int k0 = 0; k0 < LLM_DIM; k0 += 32) {
        // A tile 128x32 -> As[k][r]; 1024 float4, 4 per thread
#pragma unroll
        for (int i = 0; i < 4; i++) {
            int f = i * 256 + tid;
            int r = f >> 3;         // 8 float4 per row
            int kq = f & 7;
            int grow = row0 + r;
            float4 v = make_float4(0.f, 0.f, 0.f, 0.f);
            if (grow < N_NODES)
                v = *reinterpret_cast<const float4*>(A + (size_t)grow * LLM_DIM + k0 + kq * 4);
            As[kq * 4 + 0][r] = v.x;
            As[kq * 4 + 1][r] = v.y;
            As[kq * 4 + 2][r] = v.z;
            As[kq * 4 + 3][r] = v.w;
        }
        // B tile 32x112 -> Bs[k][c]; 1792 float2, 7 per thread
#pragma unroll
        for (int i = 0; i < 7; i++) {
            int f = i * 256 + tid;
            int kr = f / 56;
            int cq = f % 56;
            float2 v = *reinterpret_cast<const float2*>(W + (size_t)(k0 + kr) * POUT + cq * 2);
            Bs[kr][cq * 2 + 0] = v.x;
            Bs[kr][cq * 2 + 1] = v.y;
        }
        __syncthreads();
#pragma unroll
        for (int k = 0; k < 32; k++) {
            float a[8], b[7];
#pragma unroll
            for (int i = 0; i < 8; i++) a[i] = As[k][tr + 16 * i];
#pragma unroll
            for (int j = 0; j < 7; j++) b[j] = Bs[k][tc + 16 * j];
#pragma unroll
            for (int i = 0; i < 8; i++)
#pragma unroll
                for (int j = 0; j < 7; j++) acc[i][j] += a[i] * b[j];
        }
        __syncthreads();
    }
#pragma unroll
    for (int i = 0; i < 8; i++) {
        int grow = row0 + tr + 16 * i;
        if (grow >= N_NODES) continue;
#pragma unroll
        for (int j = 0; j < 7; j++) {
            int c = tc + 16 * j;
            X[(size_t)grow * HIDDEN + c] = acc[i][j] + bias[c];
        }
    }
}

// ---------------- struct embedding gather: X[:, 112:128] ----------------
__global__ void struct_fill(const int* __restrict__ sid, const float* __restrict__ emb,
                            float* __restrict__ X) {
    int t = blockIdx.x * 256 + threadIdx.x;
    if (t >= N_NODES * 16) return;
    int row = t >> 4;
    int c = t & 15;
    X[(size_t)row * HIDDEN + POUT + c] = emb[sid[row] * 16 + c];
}

// ---------------- GCN GEMM: Y = dis[i] * (X @ W) ----------------
// BM=128, BN=128, BK=32. 256 thr, each 8 rows x 8 cols.
__global__ __launch_bounds__(256) void gcn_gemm(const float* __restrict__ X,
                                                const float* __restrict__ W,
                                                const float* __restrict__ dis,
                                                float* __restrict__ Y) {
    __shared__ float As[32][129];
    __shared__ float Bs[32][132];
    const int tid = threadIdx.x;
    const int tr = tid >> 4;
    const int tc = tid & 15;
    const int row0 = blockIdx.x * 128;

    float acc[8][8];
#pragma unroll
    for (int i = 0; i < 8; i++)
#pragma unroll
        for (int j = 0; j < 8; j++) acc[i][j] = 0.f;

    for (int k0 = 0; k0 < HIDDEN; k0 += 32) {
#pragma unroll
        for (int i = 0; i < 4; i++) {
            int f = i * 256 + tid;
            int r = f >> 3;
            int kq = f & 7;
            int grow = row0 + r;
            float4 v = make_float4(0.f, 0.f, 0.f, 0.f);
            if (grow < N_NODES)
                v = *reinterpret_cast<const float4*>(X + (size_t)grow * HIDDEN + k0 + kq * 4);
            As[kq * 4 + 0][r] = v.x;
            As[kq * 4 + 1][r] = v.y;
            As[kq * 4 + 2][r] = v.z;
            As[kq * 4 + 3][r] = v.w;
        }
        // W tile 32x128: 1024 float4, 4 per thread
#pragma unroll
        for (int i = 0; i < 4; i++) {
            int f = i * 256 + tid;
            int kr = f >> 5;        // 32 float4 per row
            int cq = f & 31;
            float4 v = *reinterpret_cast<const float4*>(W + (size_t)(k0 + kr) * HIDDEN + cq * 4);
            *reinterpret_cast<float4*>(&Bs[kr][cq * 4]) = v;
        }
        __syncthreads();
#pragma unroll
        for (int k = 0; k < 32; k++) {
            float a[8], b[8];
#pragma unroll
            for (int i = 0; i < 8; i++) a[i] = As[k][tr + 16 * i];
#pragma unroll
            for (int j = 0; j < 8; j++) b[j] = Bs[k][tc + 16 * j];
#pragma unroll
            for (int i = 0; i < 8; i++)
#pragma unroll
                for (int j = 0; j < 8; j++) acc[i][j] += a[i] * b[j];
        }
        __syncthreads();
    }
#pragma unroll
    for (int i = 0; i < 8; i++) {
        int grow = row0 + tr + 16 * i;
        if (grow >= N_NODES) continue;
        float d = dis[grow];
#pragma unroll
        for (int j = 0; j < 8; j++) {
            Y[(size_t)grow * HIDDEN + tc + 16 * j] = d * acc[i][j];
        }
    }
}

// ---------------- edge scatter: agg[dst] += Y[src] ----------------
// 2 edges per 256-thread block; 128 lanes per edge (coalesced row).
__global__ __launch_bounds__(256) void scatter_add(const float* __restrict__ Y,
                                                   const int* __restrict__ eidx,
                                                   float* __restrict__ agg) {
    int t = blockIdx.x * 256 + threadIdx.x;
    int e = t >> 7;
    int c = t & 127;
    if (e >= E_EDGES) return;
    int s = eidx[e];
    int d = eidx[E_EDGES + e];
    atomicAdd(&agg[(size_t)d * HIDDEN + c], Y[(size_t)s * HIDDEN + c]);
}

// ---------------- residual + relu: X += relu(dis*(agg + Y) + b) ----------------
__global__ void finalize(float* __restrict__ X, const float* __restrict__ agg,
                         const float* __restrict__ Y, const float* __restrict__ dis,
                         const float* __restrict__ b) {
    int t = blockIdx.x * 256 + threadIdx.x;
    if (t >= N_NODES * HIDDEN) return;
    int row = t >> 7;
    int c = t & 127;
    float v = dis[row] * (agg[t] + Y[t]) + b[c];
    X[t] += fmaxf(v, 0.f);
}

// ---------------- LayerNorm over dim 128, in-place ----------------
__global__ __launch_bounds__(256) void layernorm(float* __restrict__ X,
                                                 const float* __restrict__ g,
                                                 const float* __restrict__ b) {
    int wave = threadIdx.x >> 6;
    int lane = threadIdx.x & 63;
    int row = blockIdx.x * 4 + wave;
    if (row >= N_NODES) return;
    float* xr = X + (size_t)row * HIDDEN;
    float v0 = xr[lane], v1 = xr[lane + 64];
    float s = v0 + v1;
#pragma unroll
    for (int off = 32; off; off >>= 1) s += __shfl_down(s, off);
    s = __shfl(s, 0);
    float mean = s * (1.f / 128.f);
    float d0 = v0 - mean, d1 = v1 - mean;
    float vs = d0 * d0 + d1 * d1;
#pragma unroll
    for (int off = 32; off; off >>= 1) vs += __shfl_down(vs, off);
    vs = __shfl(vs, 0);
    float inv = rsqrtf(vs * (1.f / 128.f) + 1e-5f);
    xr[lane] = d0 * inv * g[lane] + b[lane];
    xr[lane + 64] = d1 * inv * g[lane + 64] + b[lane + 64];
}

extern "C" void kernel_launch(void* const* d_in, const int* in_sizes, int n_in,
                              void* d_out, int out_size, void* d_ws, size_t ws_size,
                              hipStream_t stream) {
    const float* llm   = (const float*)d_in[0];
    const int*   sid   = (const int*)d_in[1];
    const int*   eidx  = (const int*)d_in[2];
    const float* projW = (const float*)d_in[3];
    const float* projb = (const float*)d_in[4];
    const float* emb   = (const float*)d_in[5];
    const float* gcnW  = (const float*)d_in[6];
    const float* gcnb  = (const float*)d_in[7];
    const float* lng   = (const float*)d_in[8];
    const float* lnb   = (const float*)d_in[9];

    float* X = (float*)d_out;                       // [N,128] lives in d_out
    float* Y   = (float*)d_ws;                      // [N,128]
    float* agg = Y + (size_t)N_NODES * HIDDEN;      // [N,128]
    float* dis = agg + (size_t)N_NODES * HIDDEN;    // [N] (deg then rsqrt in-place)

    deg_init<<<(N_NODES + 255) / 256, 256, 0, stream>>>(dis);
    deg_count<<<(E_EDGES + 255) / 256, 256, 0, stream>>>(eidx, dis);
    deg_rsqrt<<<(N_NODES + 255) / 256, 256, 0, stream>>>(dis);

    proj_gemm<<<(N_NODES + 127) / 128, 256, 0, stream>>>(llm, projW, projb, X);
    struct_fill<<<(N_NODES * 16 + 255) / 256, 256, 0, stream>>>(sid, emb, X);

    for (int l = 0; l < 2; l++) {
        gcn_gemm<<<(N_NODES + 127) / 128, 256, 0, stream>>>(X, gcnW + (size_t)l * HIDDEN * HIDDEN, dis, Y);
        hipMemsetAsync(agg, 0, (size_t)N_NODES * HIDDEN * sizeof(float), stream);
        scatter_add<<<(E_EDGES * HIDDEN) / 256, 256, 0, stream>>>(Y, eidx, agg);
        finalize<<<(N_NODES * HIDDEN) / 256, 256, 0, stream>>>(X, agg, Y, dis, gcnb + (size_t)l * HIDDEN);
    }
    layernorm<<<N_NODES / 4, 256, 0, stream>>>(X, lng, lnb);
}

// Round 2
// 528.276 us; speedup vs baseline: 2.1585x; 2.1585x over previous
//
#include <hip/hip_runtime.h>
#include <hip/hip_bf16.h>

#define N_NODES 50000
#define E_EDGES 600000
#define LLM_DIM 640
#define HIDDEN 128
#define POUT 112
#define NB_SCAN 98   // ceil(50000/512)

typedef __attribute__((ext_vector_type(8))) short bf16x8;
typedef __attribute__((ext_vector_type(4))) float f32x4;

__device__ inline unsigned short f2bf(float f) {
    unsigned u = __float_as_uint(f);
    u += 0x7fff + ((u >> 16) & 1);   // RNE
    return (unsigned short)(u >> 16);
}

// ---------------- degree count (int) ----------------
__global__ void deg_count(const int* __restrict__ eidx, int* __restrict__ cnt) {
    int e = blockIdx.x * 256 + threadIdx.x;
    if (e < E_EDGES) atomicAdd(&cnt[eidx[E_EDGES + e]], 1);
}

__global__ void make_dis(const int* __restrict__ cnt, float* __restrict__ dis) {
    int i = blockIdx.x * 256 + threadIdx.x;
    if (i < N_NODES) dis[i] = rsqrtf(1.0f + (float)cnt[i]);
}

// ---------------- 3-kernel exclusive scan over cnt -> offs ----------------
__global__ __launch_bounds__(256) void scan_blocksum(const int* __restrict__ cnt, int* __restrict__ bsum) {
    __shared__ int s[256];
    int b = blockIdx.x, t = threadIdx.x;
    int i0 = b * 512 + t, i1 = i0 + 256;
    int v = (i0 < N_NODES ? cnt[i0] : 0) + (i1 < N_NODES ? cnt[i1] : 0);
    s[t] = v;
    __syncthreads();
    for (int st = 128; st; st >>= 1) {
        if (t < st) s[t] += s[t + st];
        __syncthreads();
    }
    if (t == 0) bsum[b] = s[0];
}

__global__ void scan_bsum(const int* __restrict__ bsum, int* __restrict__ bpre) {
    __shared__ int s[128];
    int t = threadIdx.x;
    if (t < NB_SCAN) s[t] = bsum[t];
    __syncthreads();
    if (t == 0) {
        int a = 0;
        for (int i = 0; i < NB_SCAN; i++) { int v = s[i]; s[i] = a; a += v; }
    }
    __syncthreads();
    if (t < NB_SCAN) bpre[t] = s[t];
}

__global__ __launch_bounds__(256) void scan_offs(const int* __restrict__ cnt, const int* __restrict__ bpre,
                                                 int* __restrict__ offs) {
    __shared__ int sA[512], sB[512];
    int b = blockIdx.x, t = threadIdx.x;
    int i0 = b * 512 + t, i1 = i0 + 256;
    int v0 = (i0 < N_NODES ? cnt[i0] : 0);
    int v1 = (i1 < N_NODES ? cnt[i1] : 0);
    sA[t] = v0; sA[t + 256] = v1;
    int* src = sA; int* dst = sB;
    for (int st = 1; st < 512; st <<= 1) {
        __syncthreads();
        dst[t]       = src[t]       + (t       >= st ? src[t - st]       : 0);
        dst[t + 256] = src[t + 256] + (t + 256 >= st ? src[t + 256 - st] : 0);
        int* tmp = src; src = dst; dst = tmp;
    }
    __syncthreads();
    int base = bpre[b];
    if (i0 < N_NODES) offs[i0] = base + src[t] - v0;
    if (i1 < N_NODES) offs[i1] = base + src[t + 256] - v1;
    if (b == 0 && t == 0) offs[N_NODES] = E_EDGES;
}

__global__ void fill_srcs(const int* __restrict__ eidx, const int* __restrict__ offs,
                          int* __restrict__ pos, int* __restrict__ srcs) {
    int e = blockIdx.x * 256 + threadIdx.x;
    if (e >= E_EDGES) return;
    int s = eidx[e];
    int d = eidx[E_EDGES + e];
    int p = atomicAdd(&pos[d], 1);
    srcs[offs[d] + p] = s;
}

// ---------------- W transpose+convert: Wt[n][k] bf16 ----------------
__global__ void wt_convert(const float* __restrict__ W, unsigned short* __restrict__ Wt) {
    int idx = blockIdx.x * 256 + threadIdx.x;
    if (idx >= POUT * LLM_DIM) return;
    int n = idx / LLM_DIM;
    int k = idx - n * LLM_DIM;
    Wt[(size_t)n * LLM_DIM + k] = f2bf(W[(size_t)k * POUT + n]);
}

// ---------------- projection via bf16 MFMA ----------------
// BM=128 (4 waves x 32 rows), BN=112 (7 col tiles), BK=64.
__global__ __launch_bounds__(256) void proj_mfma(const float* __restrict__ A,
                                                 const unsigned short* __restrict__ Wt,
                                                 const float* __restrict__ bias,
                                                 float* __restrict__ X) {
    __shared__ short As[128][72];   // [row][k], stride 144B (16B multiple)
    __shared__ short Bs[112][72];   // [n][k]
    const int tid = threadIdx.x;
    const int wave = tid >> 6, lane = tid & 63;
    const int row0 = blockIdx.x * 128;
    const int l15 = lane & 15, l4 = lane >> 4;

    f32x4 acc[2][7];
#pragma unroll
    for (int i = 0; i < 2; i++)
#pragma unroll
        for (int j = 0; j < 7; j++) acc[i][j] = (f32x4){0.f, 0.f, 0.f, 0.f};

    for (int k0 = 0; k0 < LLM_DIM; k0 += 64) {
        // A tile 128x64 fp32 -> bf16 LDS. 2048 float4, 8/thread.
#pragma unroll
        for (int i = 0; i < 8; i++) {
            int f = i * 256 + tid;
            int r = f >> 4;          // 16 float4 per row
            int q = f & 15;
            int grow = row0 + r;
            float4 v = make_float4(0.f, 0.f, 0.f, 0.f);
            if (grow < N_NODES)
                v = *reinterpret_cast<const float4*>(A + (size_t)grow * LLM_DIM + k0 + q * 4);
            uint2 u;
            u.x = (unsigned)f2bf(v.x) | ((unsigned)f2bf(v.y) << 16);
            u.y = (unsigned)f2bf(v.z) | ((unsigned)f2bf(v.w) << 16);
            *reinterpret_cast<uint2*>(&As[r][q * 4]) = u;
        }
        // B tile 112x64 bf16 from pre-transposed Wt. 1792 8B chunks, 7/thread.
#pragma unroll
        for (int i = 0; i < 7; i++) {
            int f = i * 256 + tid;
            int n = f >> 4;          // 16 chunks per row
            int q = f & 15;
            uint2 v = *reinterpret_cast<const uint2*>(Wt + (size_t)n * LLM_DIM + k0 + q * 4);
            *reinterpret_cast<uint2*>(&Bs[n][q * 4]) = v;
        }
        __syncthreads();
#pragma unroll
        for (int ks = 0; ks < 2; ks++) {
            int kk = ks * 32 + l4 * 8;
            bf16x8 a0 = *reinterpret_cast<bf16x8*>(&As[wave * 32 + l15][kk]);
            bf16x8 a1 = *reinterpret_cast<bf16x8*>(&As[wave * 32 + 16 + l15][kk]);
#pragma unroll
            for (int ct = 0; ct < 7; ct++) {
                bf16x8 b = *reinterpret_cast<bf16x8*>(&Bs[ct * 16 + l15][kk]);
                acc[0][ct] = __builtin_amdgcn_mfma_f32_16x16x32_bf16(a0, b, acc[0][ct], 0, 0, 0);
                acc[1][ct] = __builtin_amdgcn_mfma_f32_16x16x32_bf16(a1, b, acc[1][ct], 0, 0, 0);
            }
        }
        __syncthreads();
    }
    // epilogue: C/D layout col=lane&15, row=(lane>>4)*4+reg
#pragma unroll
    for (int rt = 0; rt < 2; rt++)
#pragma unroll
        for (int ct = 0; ct < 7; ct++)
#pragma unroll
            for (int r = 0; r < 4; r++) {
                int row = row0 + wave * 32 + rt * 16 + l4 * 4 + r;
                int col = ct * 16 + l15;
                if (row < N_NODES)
                    X[(size_t)row * HIDDEN + col] = acc[rt][ct][r] + bias[col];
            }
}

// ---------------- struct embedding gather: X[:, 112:128] ----------------
__global__ void struct_fill(const int* __restrict__ sid, const float* __restrict__ emb,
                            float* __restrict__ X) {
    int t = blockIdx.x * 256 + threadIdx.x;
    if (t >= N_NODES * 16) return;
    int row = t >> 4;
    int c = t & 15;
    X[(size_t)row * HIDDEN + POUT + c] = emb[sid[row] * 16 + c];
}

// ---------------- GCN GEMM (fp32): Y = dis[i] * (X @ W), BM=64 ----------------
__global__ __launch_bounds__(256) void gcn_gemm(const float* __restrict__ X,
                                                const float* __restrict__ W,
                                                const float* __restrict__ dis,
                                                float* __restrict__ Y) {
    __shared__ float As[32][65];
    __shared__ float Bs[32][132];
    const int tid = threadIdx.x;
    const int tr = tid >> 4;
    const int tc = tid & 15;
    const int row0 = blockIdx.x * 64;

    float acc[4][8];
#pragma unroll
    for (int i = 0; i < 4; i++)
#pragma unroll
        for (int j = 0; j < 8; j++) acc[i][j] = 0.f;

    for (int k0 = 0; k0 < HIDDEN; k0 += 32) {
        // A tile 64x32: 512 float4, 2/thread
#pragma unroll
        for (int i = 0; i < 2; i++) {
            int f = i * 256 + tid;
            int r = f >> 3;
            int kq = f & 7;
            int grow = row0 + r;
            float4 v = make_float4(0.f, 0.f, 0.f, 0.f);
            if (grow < N_NODES)
                v = *reinterpret_cast<const float4*>(X + (size_t)grow * HIDDEN + k0 + kq * 4);
            As[kq * 4 + 0][r] = v.x;
            As[kq * 4 + 1][r] = v.y;
            As[kq * 4 + 2][r] = v.z;
            As[kq * 4 + 3][r] = v.w;
        }
        // W tile 32x128: 1024 float4, 4/thread
#pragma unroll
        for (int i = 0; i < 4; i++) {
            int f = i * 256 + tid;
            int kr = f >> 5;
            int cq = f & 31;
            float4 v = *reinterpret_cast<const float4*>(W + (size_t)(k0 + kr) * HIDDEN + cq * 4);
            *reinterpret_cast<float4*>(&Bs[kr][cq * 4]) = v;
        }
        __syncthreads();
#pragma unroll
        for (int k = 0; k < 32; k++) {
            float a[4], b[8];
#pragma unroll
            for (int i = 0; i < 4; i++) a[i] = As[k][tr + 16 * i];
#pragma unroll
            for (int j = 0; j < 8; j++) b[j] = Bs[k][tc + 16 * j];
#pragma unroll
            for (int i = 0; i < 4; i++)
#pragma unroll
                for (int j = 0; j < 8; j++) acc[i][j] += a[i] * b[j];
        }
        __syncthreads();
    }
#pragma unroll
    for (int i = 0; i < 4; i++) {
        int grow = row0 + tr + 16 * i;
        if (grow >= N_NODES) continue;
        float d = dis[grow];
#pragma unroll
        for (int j = 0; j < 8; j++)
            Y[(size_t)grow * HIDDEN + tc + 16 * j] = d * acc[i][j];
    }
}

// ---------------- fused CSR gather + finalize ----------------
// One wave per node: X[i] += relu(dis[i]*(sum_{src->i} Y[src] + Y[i]) + b)
__global__ __launch_bounds__(256) void gather_finalize(const float* __restrict__ Y,
                                                       const int* __restrict__ offs,
                                                       const int* __restrict__ srcs,
                                                       const float* __restrict__ dis,
                                                       const float* __restrict__ bias,
                                                       float* __restrict__ X) {
    int node = blockIdx.x * 4 + (threadIdx.x >> 6);
    int lane = threadIdx.x & 63;
    if (node >= N_NODES) return;
    int beg = offs[node], end = offs[node + 1];
    const float2* Y2 = reinterpret_cast<const float2*>(Y);
    float ax = 0.f, ay = 0.f;
    int e = beg;
    for (; e + 1 < end; e += 2) {
        int s0 = srcs[e], s1 = srcs[e + 1];
        float2 v0 = Y2[(size_t)s0 * 64 + lane];
        float2 v1 = Y2[(size_t)s1 * 64 + lane];
        ax += v0.x + v1.x;
        ay += v0.y + v1.y;
    }
    if (e < end) {
        float2 v = Y2[(size_t)srcs[e] * 64 + lane];
        ax += v.x;
        ay += v.y;
    }
    float dn = dis[node];
    float2 self = Y2[(size_t)node * 64 + lane];
    float2 bb = reinterpret_cast<const float2*>(bias)[lane];
    float v0 = dn * (ax + self.x) + bb.x;
    float v1 = dn * (ay + self.y) + bb.y;
    float2* X2 = reinterpret_cast<float2*>(X);
    float2 xv = X2[(size_t)node * 64 + lane];
    xv.x += fmaxf(v0, 0.f);
    xv.y += fmaxf(v1, 0.f);
    X2[(size_t)node * 64 + lane] = xv;
}

// ---------------- LayerNorm over dim 128, in-place ----------------
__global__ __launch_bounds__(256) void layernorm(float* __restrict__ X,
                                                 const float* __restrict__ g,
                                                 const float* __restrict__ b) {
    int wave = threadIdx.x >> 6;
    int lane = threadIdx.x & 63;
    int row = blockIdx.x * 4 + wave;
    if (row >= N_NODES) return;
    float* xr = X + (size_t)row * HIDDEN;
    float v0 = xr[lane], v1 = xr[lane + 64];
    float s = v0 + v1;
#pragma unroll
    for (int off = 32; off; off >>= 1) s += __shfl_down(s, off);
    s = __shfl(s, 0);
    float mean = s * (1.f / 128.f);
    float d0 = v0 - mean, d1 = v1 - mean;
    float vs = d0 * d0 + d1 * d1;
#pragma unroll
    for (int off = 32; off; off >>= 1) vs += __shfl_down(vs, off);
    vs = __shfl(vs, 0);
    float inv = rsqrtf(vs * (1.f / 128.f) + 1e-5f);
    xr[lane] = d0 * inv * g[lane] + b[lane];
    xr[lane + 64] = d1 * inv * g[lane + 64] + b[lane + 64];
}

extern "C" void kernel_launch(void* const* d_in, const int* in_sizes, int n_in,
                              void* d_out, int out_size, void* d_ws, size_t ws_size,
                              hipStream_t stream) {
    const float* llm   = (const float*)d_in[0];
    const int*   sid   = (const int*)d_in[1];
    const int*   eidx  = (const int*)d_in[2];
    const float* projW = (const float*)d_in[3];
    const float* projb = (const float*)d_in[4];
    const float* emb   = (const float*)d_in[5];
    const float* gcnW  = (const float*)d_in[6];
    const float* gcnb  = (const float*)d_in[7];
    const float* lng   = (const float*)d_in[8];
    const float* lnb   = (const float*)d_in[9];

    float* X = (float*)d_out;                          // [N,128]
    float* Y = (float*)d_ws;                           // [N,128]
    float* dis = Y + (size_t)N_NODES * HIDDEN;         // [N]
    int* cnt  = (int*)(dis + N_NODES);                 // [N]
    int* offs = cnt + N_NODES;                         // [N+1]
    int* pos  = offs + N_NODES + 1;                    // [N]
    int* bsum = pos + N_NODES;                         // [128]
    int* bpre = bsum + 128;                            // [128]
    int* srcs = bpre + 128;                            // [E]
    unsigned short* Wt = (unsigned short*)(srcs + E_EDGES);  // [112*640] bf16

    hipMemsetAsync(cnt, 0, N_NODES * sizeof(int), stream);
    hipMemsetAsync(pos, 0, N_NODES * sizeof(int), stream);

    deg_count<<<(E_EDGES + 255) / 256, 256, 0, stream>>>(eidx, cnt);
    scan_blocksum<<<NB_SCAN, 256, 0, stream>>>(cnt, bsum);
    scan_bsum<<<1, 128, 0, stream>>>(bsum, bpre);
    scan_offs<<<NB_SCAN, 256, 0, stream>>>(cnt, bpre, offs);
    make_dis<<<(N_NODES + 255) / 256, 256, 0, stream>>>(cnt, dis);
    fill_srcs<<<(E_EDGES + 255) / 256, 256, 0, stream>>>(eidx, offs, pos, srcs);

    wt_convert<<<(POUT * LLM_DIM + 255) / 256, 256, 0, stream>>>(projW, Wt);
    proj_mfma<<<(N_NODES + 127) / 128, 256, 0, stream>>>(llm, Wt, projb, X);
    struct_fill<<<(N_NODES * 16 + 255) / 256, 256, 0, stream>>>(sid, emb, X);

    for (int l = 0; l < 2; l++) {
        gcn_gemm<<<(N_NODES + 63) / 64, 256, 0, stream>>>(X, gcnW + (size_t)l * HIDDEN * HIDDEN, dis, Y);
        gather_finalize<<<(N_NODES + 3) / 4, 256, 0, stream>>>(Y, offs, srcs, dis, gcnb + (size_t)l * HIDDEN, X);
    }
    layernorm<<<N_NODES / 4, 256, 0, stream>>>(X, lng, lnb);
}

// Round 5
// 390.389 us; speedup vs baseline: 2.9210x; 1.3532x over previous
//
#include <hip/hip_runtime.h>

#define N_NODES 50000
#define E_EDGES 600000
#define LLM_DIM 640
#define HIDDEN 128
#define POUT 112
#define NB_SCAN 98   // ceil(50000/512)

typedef __attribute__((ext_vector_type(8))) short bf16x8;
typedef __attribute__((ext_vector_type(4))) float f32x4;

__device__ inline unsigned short f2bf(float f) {
    unsigned u = __float_as_uint(f);
    u += 0x7fff + ((u >> 16) & 1);   // RNE
    return (unsigned short)(u >> 16);
}
__device__ inline float bflo(unsigned v) { return __uint_as_float(v << 16); }
__device__ inline float bfhi(unsigned v) { return __uint_as_float(v & 0xffff0000u); }

// ---------------- degree count (int) ----------------
__global__ void deg_count(const int* __restrict__ eidx, int* __restrict__ cnt) {
    int e = blockIdx.x * 256 + threadIdx.x;
    if (e < E_EDGES) atomicAdd(&cnt[eidx[E_EDGES + e]], 1);
}

__global__ void make_dis(const int* __restrict__ cnt, float* __restrict__ dis) {
    int i = blockIdx.x * 256 + threadIdx.x;
    if (i < N_NODES) dis[i] = rsqrtf(1.0f + (float)cnt[i]);
}

// ---------------- 3-kernel exclusive scan over cnt -> offs ----------------
__global__ __launch_bounds__(256) void scan_blocksum(const int* __restrict__ cnt, int* __restrict__ bsum) {
    __shared__ int s[256];
    int b = blockIdx.x, t = threadIdx.x;
    int i0 = b * 512 + t, i1 = i0 + 256;
    int v = (i0 < N_NODES ? cnt[i0] : 0) + (i1 < N_NODES ? cnt[i1] : 0);
    s[t] = v;
    __syncthreads();
    for (int st = 128; st; st >>= 1) {
        if (t < st) s[t] += s[t + st];
        __syncthreads();
    }
    if (t == 0) bsum[b] = s[0];
}

__global__ void scan_bsum(const int* __restrict__ bsum, int* __restrict__ bpre) {
    __shared__ int s[128];
    int t = threadIdx.x;
    if (t < NB_SCAN) s[t] = bsum[t];
    __syncthreads();
    if (t == 0) {
        int a = 0;
        for (int i = 0; i < NB_SCAN; i++) { int v = s[i]; s[i] = a; a += v; }
    }
    __syncthreads();
    if (t < NB_SCAN) bpre[t] = s[t];
}

__global__ __launch_bounds__(256) void scan_offs(const int* __restrict__ cnt, const int* __restrict__ bpre,
                                                 int* __restrict__ offs) {
    __shared__ int sA[512], sB[512];
    int b = blockIdx.x, t = threadIdx.x;
    int i0 = b * 512 + t, i1 = i0 + 256;
    int v0 = (i0 < N_NODES ? cnt[i0] : 0);
    int v1 = (i1 < N_NODES ? cnt[i1] : 0);
    sA[t] = v0; sA[t + 256] = v1;
    int* src = sA; int* dst = sB;
    for (int st = 1; st < 512; st <<= 1) {
        __syncthreads();
        dst[t]       = src[t]       + (t       >= st ? src[t - st]       : 0);
        dst[t + 256] = src[t + 256] + (t + 256 >= st ? src[t + 256 - st] : 0);
        int* tmp = src; src = dst; dst = tmp;
    }
    __syncthreads();
    int base = bpre[b];
    if (i0 < N_NODES) offs[i0] = base + src[t] - v0;
    if (i1 < N_NODES) offs[i1] = base + src[t + 256] - v1;
    if (b == 0 && t == 0) offs[N_NODES] = E_EDGES;
}

__global__ void fill_srcs(const int* __restrict__ eidx, const int* __restrict__ offs,
                          int* __restrict__ pos, int* __restrict__ srcs) {
    int e = blockIdx.x * 256 + threadIdx.x;
    if (e >= E_EDGES) return;
    int s = eidx[e];
    int d = eidx[E_EDGES + e];
    int p = atomicAdd(&pos[d], 1);
    srcs[offs[d] + p] = s;
}

// ---------------- weight converts ----------------
__global__ void wt_convert(const float* __restrict__ W, unsigned short* __restrict__ Wt) {
    int idx = blockIdx.x * 256 + threadIdx.x;
    if (idx >= POUT * LLM_DIM) return;
    int n = idx / LLM_DIM;
    int k = idx - n * LLM_DIM;
    Wt[(size_t)n * LLM_DIM + k] = f2bf(W[(size_t)k * POUT + n]);
}

__global__ void w2_convert(const float* __restrict__ W, unsigned short* __restrict__ Wt2) {
    int idx = blockIdx.x * 256 + threadIdx.x;
    if (idx >= 2 * HIDDEN * HIDDEN) return;
    int l = idx >> 14;
    int rem = idx & 16383;
    int n = rem >> 7;
    int k = rem & 127;
    Wt2[idx] = f2bf(W[l * 16384 + k * 128 + n]);
}

// ---------------- projection via bf16 MFMA, BM=64, fused struct-emb + Xs emit ----------------
__global__ __launch_bounds__(256) void proj_mfma(const float* __restrict__ A,
                                                 const unsigned short* __restrict__ Wt,
                                                 const float* __restrict__ bias,
                                                 const float* __restrict__ emb,
                                                 const int* __restrict__ sid,
                                                 const float* __restrict__ dis,
                                                 float* __restrict__ X,
                                                 unsigned short* __restrict__ Xs) {
    __shared__ short As[64][72];    // K-tile 64 + pad
    __shared__ short Bs[112][72];
    const int tid = threadIdx.x;
    const int wave = tid >> 6, lane = tid & 63;
    const int row0 = blockIdx.x * 64;
    const int l15 = lane & 15, l4 = lane >> 4;

    f32x4 acc[7];
#pragma unroll
    for (int j = 0; j < 7; j++) acc[j] = (f32x4){0.f, 0.f, 0.f, 0.f};

    for (int k0 = 0; k0 < LLM_DIM; k0 += 64) {
        // A tile 64x64 fp32 -> bf16 LDS. 1024 float4, 4/thread, coalesced per row.
#pragma unroll
        for (int i = 0; i < 4; i++) {
            int f = i * 256 + tid;
            int r = f >> 4;          // 16 float4 per row
            int q = f & 15;
            int grow = row0 + r;
            float4 v = make_float4(0.f, 0.f, 0.f, 0.f);
            if (grow < N_NODES)
                v = *reinterpret_cast<const float4*>(A + (size_t)grow * LLM_DIM + k0 + q * 4);
            uint2 u;
            u.x = (unsigned)f2bf(v.x) | ((unsigned)f2bf(v.y) << 16);
            u.y = (unsigned)f2bf(v.z) | ((unsigned)f2bf(v.w) << 16);
            *reinterpret_cast<uint2*>(&As[r][q * 4]) = u;
        }
        // B tile 112x64 bf16. 1792 8B chunks, 7/thread.
#pragma unroll
        for (int i = 0; i < 7; i++) {
            int f = i * 256 + tid;
            int n = f >> 4;
            int q = f & 15;
            uint2 v = *reinterpret_cast<const uint2*>(Wt + (size_t)n * LLM_DIM + k0 + q * 4);
            *reinterpret_cast<uint2*>(&Bs[n][q * 4]) = v;
        }
        __syncthreads();
#pragma unroll
        for (int ks = 0; ks < 2; ks++) {
            int kk = ks * 32 + l4 * 8;
            bf16x8 a = *reinterpret_cast<bf16x8*>(&As[wave * 16 + l15][kk]);
#pragma unroll
            for (int ct = 0; ct < 7; ct++) {
                bf16x8 b = *reinterpret_cast<bf16x8*>(&Bs[ct * 16 + l15][kk]);
                acc[ct] = __builtin_amdgcn_mfma_f32_16x16x32_bf16(a, b, acc[ct], 0, 0, 0);
            }
        }
        __syncthreads();
    }
    // epilogue: rows row0 + wave*16 + l4*4 + r; cols ct*16 + l15 (+ emb cols 112..127)
#pragma unroll
    for (int r = 0; r < 4; r++) {
        int row = row0 + wave * 16 + l4 * 4 + r;
        if (row >= N_NODES) continue;
        float d = dis[row];
#pragma unroll
        for (int ct = 0; ct < 7; ct++) {
            int col = ct * 16 + l15;
            float v = acc[ct][r] + bias[col];
            X[(size_t)row * HIDDEN + col] = v;
            Xs[(size_t)row * HIDDEN + col] = f2bf(d * v);
        }
        float e = emb[sid[row] * 16 + l15];
        X[(size_t)row * HIDDEN + POUT + l15] = e;
        Xs[(size_t)row * HIDDEN + POUT + l15] = f2bf(d * e);
    }
}

// ---------------- CSR gather on bf16: Gb[i] = bf16(dis_i*(sum Xs[src] + Xs[i])) ----------------
// Xs already carries one dis factor; self-loop term is dis_i^2*x_i = dis_i*Xs_i.
__global__ __launch_bounds__(256) void gather(const unsigned short* __restrict__ Xs,
                                              const int* __restrict__ offs,
                                              const int* __restrict__ srcs,
                                              const float* __restrict__ dis,
                                              unsigned short* __restrict__ Gb) {
    int node = blockIdx.x * 4 + (threadIdx.x >> 6);
    int lane = threadIdx.x & 63;
    if (node >= N_NODES) return;
    int beg = __builtin_amdgcn_readfirstlane(offs[node]);
    int end = __builtin_amdgcn_readfirstlane(offs[node + 1]);
    const unsigned* X32 = reinterpret_cast<const unsigned*>(Xs);
    float ax = 0.f, ay = 0.f;
    int e = beg;
    while (e < end) {
        int n = end - e;
        if (n > 64) n = 64;
        int idx = (lane < n) ? srcs[e + lane] : 0;
        int j = 0;
        for (; j + 4 <= n; j += 4) {
            int s0 = __shfl(idx, j);
            int s1 = __shfl(idx, j + 1);
            int s2 = __shfl(idx, j + 2);
            int s3 = __shfl(idx, j + 3);
            unsigned v0 = X32[(size_t)s0 * 64 + lane];
            unsigned v1 = X32[(size_t)s1 * 64 + lane];
            unsigned v2 = X32[(size_t)s2 * 64 + lane];
            unsigned v3 = X32[(size_t)s3 * 64 + lane];
            ax += (bflo(v0) + bflo(v1)) + (bflo(v2) + bflo(v3));
            ay += (bfhi(v0) + bfhi(v1)) + (bfhi(v2) + bfhi(v3));
        }
        for (; j < n; j++) {
            int s = __shfl(idx, j);
            unsigned v = X32[(size_t)s * 64 + lane];
            ax += bflo(v);
            ay += bfhi(v);
        }
        e += 64;
    }
    float d = dis[node];
    unsigned sv = X32[(size_t)node * 64 + lane];
    ax = d * (ax + bflo(sv));   // self term = dis_i * Xs_i
    ay = d * (ay + bfhi(sv));
    reinterpret_cast<unsigned*>(Gb)[(size_t)node * 64 + lane] =
        (unsigned)f2bf(ax) | ((unsigned)f2bf(ay) << 16);
}

// ---------------- fused GEMM + residual + relu (+Xs emit / +LayerNorm) ----------------
// MODE 0: X += relu(Gb@W + b); Xs2 = bf16(dis*X)
// MODE 1: X = LayerNorm(X + relu(Gb@W + b))
template <int MODE>
__global__ __launch_bounds__(256) void gemm_fin(const unsigned short* __restrict__ Gb,
                                                const unsigned short* __restrict__ Wt2,
                                                const float* __restrict__ bias,
                                                const float* __restrict__ dis,
                                                const float* __restrict__ lng,
                                                const float* __restrict__ lnb,
                                                float* __restrict__ X,
                                                unsigned short* __restrict__ Xs2) {
    __shared__ short As[64][136];    // K=128 + 8 pad  (was [72]: OOB — the round-3/4 bug)
    __shared__ short Bs[128][136];
    const int tid = threadIdx.x;
    const int wave = tid >> 6, lane = tid & 63;
    const int row0 = blockIdx.x * 64;
    const int l15 = lane & 15, l4 = lane >> 4;

    // stage A 64x128 bf16: 1024 uint4, 4/thread
#pragma unroll
    for (int i = 0; i < 4; i++) {
        int f = i * 256 + tid;
        int r = f >> 4;
        int q = f & 15;
        int grow = row0 + r;
        uint4 v = make_uint4(0, 0, 0, 0);
        if (grow < N_NODES)
            v = reinterpret_cast<const uint4*>(Gb + (size_t)grow * HIDDEN)[q];
        *reinterpret_cast<uint4*>(&As[r][q * 8]) = v;
    }
    // stage B 128x128 bf16: 2048 uint4, 8/thread
#pragma unroll
    for (int i = 0; i < 8; i++) {
        int f = i * 256 + tid;
        int r = f >> 4;
        int q = f & 15;
        uint4 v = reinterpret_cast<const uint4*>(Wt2 + (size_t)r * HIDDEN)[q];
        *reinterpret_cast<uint4*>(&Bs[r][q * 8]) = v;
    }
    __syncthreads();

    f32x4 acc[8];
#pragma unroll
    for (int j = 0; j < 8; j++) acc[j] = (f32x4){0.f, 0.f, 0.f, 0.f};
#pragma unroll
    for (int ks = 0; ks < 4; ks++) {
        int kk = ks * 32 + l4 * 8;
        bf16x8 a = *reinterpret_cast<bf16x8*>(&As[wave * 16 + l15][kk]);
#pragma unroll
        for (int ct = 0; ct < 8; ct++) {
            bf16x8 b = *reinterpret_cast<bf16x8*>(&Bs[ct * 16 + l15][kk]);
            acc[ct] = __builtin_amdgcn_mfma_f32_16x16x32_bf16(a, b, acc[ct], 0, 0, 0);
        }
    }

    // epilogue
    float bcol[8];
#pragma unroll
    for (int ct = 0; ct < 8; ct++) bcol[ct] = bias[ct * 16 + l15];

    float vv[8][4];
#pragma unroll
    for (int r = 0; r < 4; r++) {
        int row = row0 + wave * 16 + l4 * 4 + r;
        bool ok = row < N_NODES;
#pragma unroll
        for (int ct = 0; ct < 8; ct++) {
            float xo = ok ? X[(size_t)row * HIDDEN + ct * 16 + l15] : 0.f;
            vv[ct][r] = xo + fmaxf(acc[ct][r] + bcol[ct], 0.f);
        }
    }

    if (MODE == 0) {
#pragma unroll
        for (int r = 0; r < 4; r++) {
            int row = row0 + wave * 16 + l4 * 4 + r;
            if (row >= N_NODES) continue;
            float d = dis[row];
#pragma unroll
            for (int ct = 0; ct < 8; ct++) {
                int col = ct * 16 + l15;
                X[(size_t)row * HIDDEN + col] = vv[ct][r];
                Xs2[(size_t)row * HIDDEN + col] = f2bf(d * vv[ct][r]);
            }
        }
    } else {
        float s[4], q2[4];
#pragma unroll
        for (int r = 0; r < 4; r++) {
            s[r] = 0.f; q2[r] = 0.f;
#pragma unroll
            for (int ct = 0; ct < 8; ct++) {
                s[r] += vv[ct][r];
                q2[r] += vv[ct][r] * vv[ct][r];
            }
        }
#pragma unroll
        for (int off = 1; off < 16; off <<= 1) {
#pragma unroll
            for (int r = 0; r < 4; r++) {
                s[r] += __shfl_xor(s[r], off);
                q2[r] += __shfl_xor(q2[r], off);
            }
        }
        float gcol[8], bcol2[8];
#pragma unroll
        for (int ct = 0; ct < 8; ct++) {
            gcol[ct] = lng[ct * 16 + l15];
            bcol2[ct] = lnb[ct * 16 + l15];
        }
#pragma unroll
        for (int r = 0; r < 4; r++) {
            int row = row0 + wave * 16 + l4 * 4 + r;
            if (row >= N_NODES) continue;
            float mean = s[r] * (1.f / 128.f);
            float var = q2[r] * (1.f / 128.f) - mean * mean;
            float inv = rsqrtf(var + 1e-5f);
#pragma unroll
            for (int ct = 0; ct < 8; ct++) {
                int col = ct * 16 + l15;
                X[(size_t)row * HIDDEN + col] = (vv[ct][r] - mean) * inv * gcol[ct] + bcol2[ct];
            }
        }
    }
}

extern "C" void kernel_launch(void* const* d_in, const int* in_sizes, int n_in,
                              void* d_out, int out_size, void* d_ws, size_t ws_size,
                              hipStream_t stream) {
    const float* llm   = (const float*)d_in[0];
    const int*   sid   = (const int*)d_in[1];
    const int*   eidx  = (const int*)d_in[2];
    const float* projW = (const float*)d_in[3];
    const float* projb = (const float*)d_in[4];
    const float* emb   = (const float*)d_in[5];
    const float* gcnW  = (const float*)d_in[6];
    const float* gcnb  = (const float*)d_in[7];
    const float* lng   = (const float*)d_in[8];
    const float* lnb   = (const float*)d_in[9];

    float* X = (float*)d_out;                                   // [N,128] fp32
    unsigned short* Xs = (unsigned short*)d_ws;                 // [N,128] bf16
    unsigned short* Gb = Xs + (size_t)N_NODES * HIDDEN;         // [N,128] bf16
    unsigned short* Wt = Gb;                                    // [112,640] bf16 (overlaps Gb: dead before gather)
    unsigned short* Wt2 = Gb + (size_t)N_NODES * HIDDEN;        // [2,128,128] bf16
    float* dis = (float*)(Wt2 + 2 * HIDDEN * HIDDEN);           // [N]
    int* cnt  = (int*)(dis + N_NODES);                          // [N] (reused as pos)
    int* offs = cnt + N_NODES;                                  // [N+1]
    int* bsum = offs + N_NODES + 1;                             // [128]
    int* bpre = bsum + 128;                                     // [128]
    int* srcs = bpre + 128;                                     // [E]

    hipMemsetAsync(cnt, 0, N_NODES * sizeof(int), stream);
    deg_count<<<(E_EDGES + 255) / 256, 256, 0, stream>>>(eidx, cnt);
    make_dis<<<(N_NODES + 255) / 256, 256, 0, stream>>>(cnt, dis);
    scan_blocksum<<<NB_SCAN, 256, 0, stream>>>(cnt, bsum);
    scan_bsum<<<1, 128, 0, stream>>>(bsum, bpre);
    scan_offs<<<NB_SCAN, 256, 0, stream>>>(cnt, bpre, offs);
    hipMemsetAsync(cnt, 0, N_NODES * sizeof(int), stream);      // cnt -> pos
    fill_srcs<<<(E_EDGES + 255) / 256, 256, 0, stream>>>(eidx, offs, cnt, srcs);

    wt_convert<<<(POUT * LLM_DIM + 255) / 256, 256, 0, stream>>>(projW, Wt);
    w2_convert<<<(2 * HIDDEN * HIDDEN + 255) / 256, 256, 0, stream>>>(gcnW, Wt2);

    proj_mfma<<<(N_NODES + 63) / 64, 256, 0, stream>>>(llm, Wt, projb, emb, sid, dis, X, Xs);

    gather<<<(N_NODES + 3) / 4, 256, 0, stream>>>(Xs, offs, srcs, dis, Gb);
    gemm_fin<0><<<(N_NODES + 63) / 64, 256, 0, stream>>>(Gb, Wt2, gcnb, dis, lng, lnb, X, Xs);
    gather<<<(N_NODES + 3) / 4, 256, 0, stream>>>(Xs, offs, srcs, dis, Gb);
    gemm_fin<1><<<(N_NODES + 63) / 64, 256, 0, stream>>>(Gb, Wt2 + HIDDEN * HIDDEN, gcnb + HIDDEN, dis, lng, lnb, X, Xs);
}